// Round 6
// baseline (7499.545 us; speedup 1.0000x reference)
//
#include <hip/hip_runtime.h>
#include <cfloat>

// Farthest Point Sampling: B=32, N=200000, M=128.
// 8 blocks/batch x 1024 threads, 1 block/CU (LDS-forced), XCD-local batches.
// Per thread 25 points: 17 xyz+md in VGPRs, 8 in SoA LDS (conflict-free b32).
// One __syncthreads per iteration; intra-block argmax via LDS atomicMax on a
// monotone (valbits<<32)|~idx key; cross-block via u64 tag slots; every wave
// polls + reduces + fetches winner coords itself (no relay).
#define B_    32
#define N_    200000
#define M_    128
#define BPB   8                    // blocks per batch
#define T_    1024                 // threads per block
#define PV    17                   // points in VGPRs
#define PL    8                    // points in LDS (SoA)
#define PT    (PV + PL)            // 25; 8*1024*25 = 204800 >= N
#define CHUNK (T_ * PT)            // 25600 points per block

#define SPIN_CAP (1 << 20)         // safety valve: never hang the container

__global__ __launch_bounds__(T_)
void fps_kernel(const float* __restrict__ pts, int* __restrict__ out,
                unsigned long long* __restrict__ tags) {
  const int tid = threadIdx.x;
  const int bid = blockIdx.x;
  // XCD-local batches (blocks round-robin XCDs by bid&7): all 8 blocks of a
  // batch land on one XCD -> tag traffic stays in that XCD's L2.
  const int xcd = bid & 7;
  const int sl8 = bid >> 3;
  const int b   = ((sl8 >> 3) << 3) | xcd;   // batch
  const int c   = sl8 & 7;                   // chunk within batch
  const int lane = tid & 63;

  const float* __restrict__ P = pts + (size_t)b * (size_t)(N_ * 3);
  const int base = c * CHUNK + tid;          // this thread's j=0 global index

  // SoA: all accesses stride-4B -> bank = tid%32 -> conflict-free.
  // 4 arrays * 8 * 1024 * 4B = 128 KiB -> exactly 1 block/CU.
  __shared__ float sx[PL][T_], sy[PL][T_], sz[PL][T_], smd[PL][T_];
  __shared__ unsigned long long sKey[2];     // parity-rotated block argmax key

  if (tid == 0) { sKey[0] = 0ull; sKey[1] = 0ull; }

  // ---- one-time load ----
  float vx[PV], vy[PV], vz[PV], md[PV];
  #pragma unroll
  for (int j = 0; j < PV; ++j) {
    int g = base + j * T_;
    if (g < N_) {
      const float* p = P + (size_t)g * 3;
      vx[j] = p[0]; vy[j] = p[1]; vz[j] = p[2];
      md[j] = __builtin_huge_valf();
    } else {
      // md=0 (NOT -FLT_MAX): keys require md>=0, and 0 never wins argmax
      // while any positive min-dist exists; idx tie-break loses too (bigger).
      vx[j] = vy[j] = vz[j] = 0.f; md[j] = 0.0f;
    }
  }
  #pragma unroll
  for (int k = 0; k < PL; ++k) {
    int g = base + (PV + k) * T_;
    if (g < N_) {
      const float* p = P + (size_t)g * 3;
      sx[k][tid] = p[0]; sy[k][tid] = p[1]; sz[k][tid] = p[2];
      smd[k][tid] = __builtin_huge_valf();
    } else {
      sx[k][tid] = 0.f; sy[k][tid] = 0.f; sz[k][tid] = 0.f; smd[k][tid] = 0.0f;
    }
  }

  float cx = P[0], cy = P[1], cz = P[2];     // initial center = point 0
  if (c == 0 && tid == 0) out[b * M_ + 0] = 0;
  __syncthreads();                           // sKey/LDS init visible

  for (int it = 1; it < M_; ++it) {
    // ---- distance + running-min + 4-chain argmax ----
    // No exclusion select: chosen point's self-distance is exactly 0;
    // min(md,0)=0 never beats any positive min-dist (matches ref sequence).
    float bv[4] = {-FLT_MAX, -FLT_MAX, -FLT_MAX, -FLT_MAX};
    int   bi[4] = {0x7FFFFFFF, 0x7FFFFFFF, 0x7FFFFFFF, 0x7FFFFFFF};

    #pragma unroll
    for (int j = 0; j < PV; ++j) {
      float dx = __fsub_rn(vx[j], cx);
      float dy = __fsub_rn(vy[j], cy);
      float dz = __fsub_rn(vz[j], cz);
      // numpy: ((dx*dx + dy*dy) + dz*dz), rn, no FMA contraction
      float d  = __fadd_rn(__fadd_rn(__fmul_rn(dx, dx), __fmul_rn(dy, dy)),
                           __fmul_rn(dz, dz));
      float m  = fminf(md[j], d);            // np.minimum
      md[j] = m;
      const int q = j & 3;
      bool take = m > bv[q];                 // ascending index: strict >
      bv[q] = take ? m : bv[q];
      bi[q] = take ? (base + j * T_) : bi[q];
    }
    #pragma unroll
    for (int k = 0; k < PL; ++k) {
      const int j = PV + k;
      float X = sx[k][tid], Y = sy[k][tid], Z = sz[k][tid], M0 = smd[k][tid];
      float dx = __fsub_rn(X, cx);
      float dy = __fsub_rn(Y, cy);
      float dz = __fsub_rn(Z, cz);
      float d  = __fadd_rn(__fadd_rn(__fmul_rn(dx, dx), __fmul_rn(dy, dy)),
                           __fmul_rn(dz, dz));
      float m  = fminf(M0, d);
      smd[k][tid] = m;                       // b32 write, conflict-free
      const int q = j & 3;
      bool take = m > bv[q];
      bv[q] = take ? m : bv[q];
      bi[q] = take ? (base + j * T_) : bi[q];
    }
    // merge 4 chains (tie -> smaller index = first occurrence)
    float tv = bv[0]; int ti = bi[0];
    #pragma unroll
    for (int q = 1; q < 4; ++q) {
      bool take = (bv[q] > tv) || (bv[q] == tv && bi[q] < ti);
      tv = take ? bv[q] : tv;
      ti = take ? bi[q] : ti;
    }

    // ---- wave reduction (64 lanes) ----
    #pragma unroll
    for (int o = 32; o > 0; o >>= 1) {
      float ov = __shfl_xor(tv, o);
      int   oi = __shfl_xor(ti, o);
      bool take = (ov > tv) || (ov == tv && oi < ti);
      tv = take ? ov : tv;
      ti = take ? oi : ti;
    }

    // ---- intra-block reduce: one LDS atomicMax per wave ----
    // key = (bits(md)<<32) | ~idx : md>=0 so float bits are monotone;
    // equal values -> larger ~idx wins = smaller idx (np first-occurrence).
    if (lane == 0) {
      unsigned long long key =
          ((unsigned long long)__float_as_uint(tv) << 32) |
          (unsigned long long)(~(unsigned)ti);
      atomicMax(&sKey[it & 1], key);
    }
    if (tid == 0) sKey[(it & 1) ^ 1] = 0ull; // reset other slot pre-barrier:
                                             // all its writers are post-barrier
    __syncthreads();

    // ---- publish block winner (tid0), then ALL waves poll independently ----
    unsigned long long* grp = tags + (((b << 1) + (it & 1)) << 3);
    if (tid == 0) {
      unsigned long long k = sKey[it & 1];
      unsigned vbits = (unsigned)(k >> 32);
      unsigned idx   = ~(unsigned)k;
      unsigned long long tg =
          ((unsigned long long)vbits << 32) |
          ((unsigned long long)(idx & 0x3FFFF) << 7) | (unsigned)it;
      __hip_atomic_store(grp + c, tg, __ATOMIC_RELEASE, __HIP_MEMORY_SCOPE_AGENT);
    }

    unsigned long long t = 0;
    {
      int sp = 0;
      for (;;) {
        if (lane < BPB)
          t = __hip_atomic_load(grp + lane, __ATOMIC_ACQUIRE, __HIP_MEMORY_SCOPE_AGENT);
        bool ok = (lane >= BPB) || ((t & 127ull) == (unsigned long long)(unsigned)it);
        if (__all(ok)) break;
        if (++sp > SPIN_CAP) break;          // wrong answer >> dead container
        __builtin_amdgcn_s_sleep(1);
      }
    }
    float cv = (lane < BPB) ? __uint_as_float((unsigned)(t >> 32)) : -FLT_MAX;
    int   ci = (lane < BPB) ? (int)((t >> 7) & 0x3FFFF) : 0x7FFFFFFF;
    #pragma unroll
    for (int o = 4; o > 0; o >>= 1) {
      float ov = __shfl_xor(cv, o);
      int   oi = __shfl_xor(ci, o);
      bool take = (ov > cv) || (ov == cv && oi < ci);
      cv = take ? ov : cv;
      ci = take ? oi : ci;
    }
    ci = __shfl(ci, 0);                      // broadcast to all 64 lanes

    if (c == 0 && tid == 0) out[b * M_ + it] = ci;

    // winner coords: same address across lanes -> single broadcast request;
    // P is read-only input, L1/L2-warm after the first streaming pass.
    const float* pw = P + (size_t)ci * 3;
    cx = pw[0]; cy = pw[1]; cz = pw[2];
  }
}

extern "C" void kernel_launch(void* const* d_in, const int* in_sizes, int n_in,
                              void* d_out, int out_size, void* d_ws, size_t ws_size,
                              hipStream_t stream) {
  const float*        pts  = (const float*)d_in[0];
  int*                out  = (int*)d_out;
  unsigned long long* tags = (unsigned long long*)d_ws;

  // zero tag slots each launch (tag 0 never matches it>=1); capture-safe
  hipMemsetAsync(d_ws, 0, (size_t)B_ * 2 * BPB * sizeof(unsigned long long), stream);

  // 128 KiB LDS/block -> 1 block/CU; grid == 256 == CU count -> co-resident.
  fps_kernel<<<dim3(B_ * BPB), dim3(T_), 0, stream>>>(pts, out, tags);
}

// Round 7
// 528.980 us; speedup vs baseline: 14.1774x; 14.1774x over previous
//
#include <hip/hip_runtime.h>
#include <cfloat>

// Farthest Point Sampling: B=32, N=200000, M=128.
// r4 skeleton (measured best) + XCD-local batches + relaxed-only tag protocol
// (no acquire -> no buffer_inv) + no-exclusion scan + publish-early/fetch-late.
// 8 blocks/batch x 1024 threads, 1 block/CU (LDS-forced).
// Per thread 25 points: 13 xyz in VGPRs + 12 xyz in LDS float4; md[25] in VGPRs.
#define B_    32
#define N_    200000
#define M_    128
#define BPB   8                    // blocks per batch
#define T_    1024                 // threads per block
#define PV    13                   // points with xyz in VGPRs
#define PL    12                   // points with xyz in LDS (3 float4 groups)
#define PT    (PV + PL)            // 25; 8*1024*25 = 204800 >= N
#define CHUNK (T_ * PT)            // 25600 points per block

#define SPIN_CAP (1 << 20)         // safety valve: never hang the container

__global__ __launch_bounds__(T_, 4)
void fps_kernel(const float* __restrict__ pts, int* __restrict__ out,
                unsigned long long* __restrict__ tags) {
  const int tid = threadIdx.x;
  const int bid = blockIdx.x;
  // XCD-local batches: blocks round-robin XCDs by bid&7 (measured m09).
  // All 8 blocks of a batch -> one XCD; that batch's 2.4MB of points fits the
  // XCD's 4MB L2 -> tag exchange AND coord fetch stay L2-local.
  const int xcd = bid & 7;
  const int sl8 = bid >> 3;                  // 0..31 within this XCD
  const int b   = ((sl8 >> 3) << 3) | xcd;   // batch (b&7 == xcd)
  const int c   = sl8 & 7;                   // chunk within batch
  const int wave = tid >> 6;
  const int lane = tid & 63;

  const float* __restrict__ P = pts + (size_t)b * (size_t)(N_ * 3);
  const int base = c * CHUNK + tid;          // this thread's j=0 global index

  // 3 arrays x [3][1024] float4 = 144 KiB -> exactly 1 block/CU.
  // Thread-private columns, stride-16B b128 pattern: conflict-free, no syncs.
  __shared__ float4 sX[3][T_], sY[3][T_], sZ[3][T_];
  __shared__ float  sv[16];
  __shared__ int    si[16];
  __shared__ int    wfar;
  __shared__ float  wx, wy, wz;

  // ---- one-time load ----
  float vx[PV], vy[PV], vz[PV], md[PT];
  #pragma unroll
  for (int j = 0; j < PV; ++j) {
    int g = base + j * T_;
    if (g < N_) {
      const float* p = P + (size_t)g * 3;
      vx[j] = p[0]; vy[j] = p[1]; vz[j] = p[2];
      md[j] = __builtin_huge_valf();
    } else { vx[j] = vy[j] = vz[j] = 0.f; md[j] = -FLT_MAX; }
  }
  #pragma unroll
  for (int grp = 0; grp < 3; ++grp) {
    float qx[4], qy[4], qz[4];
    #pragma unroll
    for (int q = 0; q < 4; ++q) {
      int j = PV + grp * 4 + q;
      int g = base + j * T_;
      if (g < N_) {
        const float* p = P + (size_t)g * 3;
        qx[q] = p[0]; qy[q] = p[1]; qz[q] = p[2];
        md[j] = __builtin_huge_valf();
      } else { qx[q] = qy[q] = qz[q] = 0.f; md[j] = -FLT_MAX; }
    }
    sX[grp][tid] = make_float4(qx[0], qx[1], qx[2], qx[3]);
    sY[grp][tid] = make_float4(qy[0], qy[1], qy[2], qy[3]);
    sZ[grp][tid] = make_float4(qz[0], qz[1], qz[2], qz[3]);
  }

  float cx = P[0], cy = P[1], cz = P[2];     // initial center = point 0
  if (c == 0 && tid == 0) out[b * M_ + 0] = 0;

  for (int it = 1; it < M_; ++it) {
    // ---- distance + running-min + 4-chain argmax (j tracked, 5 bits) ----
    // No exclusion select: the chosen point's self-distance is exactly 0
    // (coords bit-exact), min(md,0)=0 never beats any positive min-dist, so
    // the argmax sequence matches the reference (proven r5/r6).
    float bv[4] = {-FLT_MAX, -FLT_MAX, -FLT_MAX, -FLT_MAX};
    int   bj[4] = {0x7FFF, 0x7FFF, 0x7FFF, 0x7FFF};

    #pragma unroll
    for (int j = 0; j < PV; ++j) {
      float dx = __fsub_rn(vx[j], cx);
      float dy = __fsub_rn(vy[j], cy);
      float dz = __fsub_rn(vz[j], cz);
      // numpy: ((dx*dx + dy*dy) + dz*dz), rn, no FMA contraction
      float d  = __fadd_rn(__fadd_rn(__fmul_rn(dx, dx), __fmul_rn(dy, dy)),
                           __fmul_rn(dz, dz));
      float m  = fminf(md[j], d);            // np.minimum
      md[j] = m;
      const int q = j & 3;
      bool take = m > bv[q];                 // ascending j: strict >
      bv[q] = take ? m : bv[q];
      bj[q] = take ? j : bj[q];
    }
    #pragma unroll
    for (int grp = 0; grp < 3; ++grp) {
      float4 qx = sX[grp][tid], qy = sY[grp][tid], qz = sZ[grp][tid];
      #pragma unroll
      for (int q4 = 0; q4 < 4; ++q4) {
        const int j = PV + grp * 4 + q4;
        float X = (q4 == 0) ? qx.x : (q4 == 1) ? qx.y : (q4 == 2) ? qx.z : qx.w;
        float Y = (q4 == 0) ? qy.x : (q4 == 1) ? qy.y : (q4 == 2) ? qy.z : qy.w;
        float Z = (q4 == 0) ? qz.x : (q4 == 1) ? qz.y : (q4 == 2) ? qz.z : qz.w;
        float dx = __fsub_rn(X, cx);
        float dy = __fsub_rn(Y, cy);
        float dz = __fsub_rn(Z, cz);
        float d  = __fadd_rn(__fadd_rn(__fmul_rn(dx, dx), __fmul_rn(dy, dy)),
                             __fmul_rn(dz, dz));
        float m  = fminf(md[j], d);
        md[j] = m;
        const int q = j & 3;
        bool take = m > bv[q];
        bv[q] = take ? m : bv[q];
        bj[q] = take ? j : bj[q];
      }
    }
    // merge 4 chains (tie -> smaller j = smaller global idx = first occurrence)
    float tv = bv[0]; int tj = bj[0];
    #pragma unroll
    for (int q = 1; q < 4; ++q) {
      bool take = (bv[q] > tv) || (bv[q] == tv && bj[q] < tj);
      tv = take ? bv[q] : tv;
      tj = take ? bj[q] : tj;
    }
    int ti = base + tj * T_;                 // reconstruct global idx once

    // ---- wave reduction (64 lanes) ----
    #pragma unroll
    for (int o = 32; o > 0; o >>= 1) {
      float ov = __shfl_xor(tv, o);
      int   oi = __shfl_xor(ti, o);
      bool take = (ov > tv) || (ov == tv && oi < ti);
      tv = take ? ov : tv;
      ti = take ? oi : ti;
    }
    if (lane == 0) { sv[wave] = tv; si[wave] = ti; }
    __syncthreads();

    if (wave == 0) {
      // cross-wave reduce (16 entries)
      float v = (lane < 16) ? sv[lane] : -FLT_MAX;
      int   i = (lane < 16) ? si[lane] : 0x7FFFFFFF;
      #pragma unroll
      for (int o = 8; o > 0; o >>= 1) {
        float ov = __shfl_xor(v, o);
        int   oi = __shfl_xor(i, o);
        bool take = (ov > v) || (ov == v && oi < i);
        v = take ? ov : v;
        i = take ? oi : i;
      }
      // publish IMMEDIATELY: tag = (valbits<<32)|(idx<<7)|iter carries the
      // whole message in one atomic word -> RELAXED suffices, no buffer_inv.
      unsigned long long* grp = tags + (((b << 1) + (it & 1)) << 3);
      if (lane == 0) {
        unsigned long long tg =
            ((unsigned long long)__float_as_uint(v) << 32) |
            ((unsigned long long)(unsigned)i << 7) | (unsigned)it;
        __hip_atomic_store(grp + c, tg, __ATOMIC_RELAXED, __HIP_MEMORY_SCOPE_AGENT);
      }
      // poll the 8 block tags (lanes 0..7, relaxed, XCD-local L2 line)
      unsigned long long t = 0;
      if (lane < BPB) {
        int sp = 0;
        for (;;) {
          t = __hip_atomic_load(grp + lane, __ATOMIC_RELAXED, __HIP_MEMORY_SCOPE_AGENT);
          if ((t & 127ull) == (unsigned long long)(unsigned)it) break;
          if (++sp > SPIN_CAP) break;        // wrong answer >> dead container
          __builtin_amdgcn_s_sleep(1);
        }
      }
      float cv = (lane < BPB) ? __uint_as_float((unsigned)(t >> 32)) : -FLT_MAX;
      int   ci = (lane < BPB) ? (int)((t >> 7) & 0x3FFFF) : 0x7FFFFFFF;
      #pragma unroll
      for (int o = 4; o > 0; o >>= 1) {
        float ov = __shfl_xor(cv, o);
        int   oi = __shfl_xor(ci, o);
        bool take = (ov > cv) || (ov == cv && oi < ci);
        cv = take ? ov : cv;
        ci = take ? oi : ci;
      }
      if (lane == 0) {
        if (c == 0) out[b * M_ + it] = ci;   // fire-and-forget
        // winner coords: P is read-only (no coherence needed); batch data is
        // L2-resident on this XCD -> ~200cy. Off the publish critical path.
        const float* pw = P + (size_t)ci * 3;
        wfar = ci; wx = pw[0]; wy = pw[1]; wz = pw[2];
      }
    }
    __syncthreads();
    cx = wx; cy = wy; cz = wz; (void)wfar;
  }
}

extern "C" void kernel_launch(void* const* d_in, const int* in_sizes, int n_in,
                              void* d_out, int out_size, void* d_ws, size_t ws_size,
                              hipStream_t stream) {
  const float*        pts  = (const float*)d_in[0];
  int*                out  = (int*)d_out;
  unsigned long long* tags = (unsigned long long*)d_ws;

  // zero tag slots each launch (tag 0 never matches it>=1); capture-safe
  hipMemsetAsync(d_ws, 0, (size_t)B_ * 2 * BPB * sizeof(unsigned long long), stream);

  // 144 KiB LDS/block -> 1 block/CU; grid == 256 == CU count -> co-resident.
  fps_kernel<<<dim3(B_ * BPB), dim3(T_), 0, stream>>>(pts, out, tags);
}